// Round 12
// baseline (523.744 us; speedup 1.0000x reference)
//
#include <hip/hip_runtime.h>
#include <hip/hip_bf16.h>
#include <math.h>

typedef unsigned int uint;
typedef unsigned short ushort;
typedef __attribute__((ext_vector_type(8))) short bf16x8;
typedef __attribute__((ext_vector_type(4))) float f32x4;

__device__ __forceinline__ float bu2f(ushort u){ union{uint u; float f;} v; v.u = ((uint)u)<<16; return v.f; }
__device__ __forceinline__ ushort f2bu(float x){ union{float f; uint u;} v; v.f = x; uint r = (v.u + 0x7FFFu + ((v.u>>16)&1u))>>16; return (ushort)r; }
__device__ __forceinline__ uint pack2(float a, float b){ return (uint)f2bu(a) | ((uint)f2bu(b) << 16); }
// HW packed f32->bf16 (RNE, bit-identical to f2bu for non-NaN), 1 VALU op. [gfx950]
__device__ __forceinline__ uint cvtpk2(float a, float b){
    uint r; asm("v_cvt_pk_bf16_f32 %0, %1, %2" : "=v"(r) : "v"(a), "v"(b)); return r;
}
// Async global->LDS DMA, 16B/lane: dest = wave-uniform LDS base + lane*16.
__device__ __forceinline__ void gload16(const ushort* g, ushort* l){
    __builtin_amdgcn_global_load_lds(
        (const __attribute__((address_space(1))) uint*)g,
        (__attribute__((address_space(3))) uint*)l, 16, 0, 0);
}

#define GEPI_IS0   0
#define GEPI_RELU  3
#define GEPI_MLP2  4
#define GEPI_OUT   5
#define GEPI_MLP2L 6   // last-iter MLP2: slots f32 is dead afterwards -> skip store

// LDS tile: [R][32] ushorts, NO pad; 16B chunk c of row r stored at slot
// (c ^ (r>>1))&3.  Conflict-free on both sides (verified: 0 conflicts).
#define SWZ(r, c) (((r) << 5) + ((((c) ^ ((r) >> 1)) & 3) << 3))

// ---- small-GEMM: 64x64 tile, 4 waves (2x2) of 32x32, gload_lds staging ----
// 1D grid with the kv-proven bijective XCD swizzle.
template<int EPI, int CB>
__global__ __launch_bounds__(256) void gemm64(
    const ushort* __restrict__ Abf, int lda,
    const ushort* __restrict__ Bt,
    const float* __restrict__ xb0,
    float* __restrict__ fp0,
    ushort* __restrict__ up0, ushort* __restrict__ up1,
    int M, int N, int K)
{
    __shared__ ushort As[64 * 32];
    __shared__ ushort Bs[64 * 32];
    int tid = threadIdx.x;
    int wave = tid >> 6, lane = tid & 63;
    int wr = wave >> 1, wc = wave & 1;
    int quad = lane >> 4, l15 = lane & 15;

    constexpr int LCB = (CB == 4) ? 2 : (CB == 8) ? 3 : 5;   // log2(CB): 4,8,32
    int bid = blockIdx.x;
    int x8  = bid & 7;
    int tt  = bid >> 3;
    int cb  = tt & (CB - 1);
    int rb  = ((tt >> LCB) << 3) + x8;     // bijective
    int row0 = rb * 64, col0 = cb * 64;

    int r   = (wave << 4) + (lane >> 2);
    int csw = ((((lane & 3) ^ (r >> 1)) & 3) << 3);
    ushort* Alds = &As[wave << 9];
    ushort* Blds = &Bs[wave << 9];
    const ushort* Ag = Abf + (size_t)(row0 + r) * lda + csw;
    const ushort* Bg = Bt  + (size_t)(col0 + r) * K   + csw;

    f32x4 acc[2][2];
    #pragma unroll
    for (int i = 0; i < 2; i++)
        #pragma unroll
        for (int j = 0; j < 2; j++) acc[i][j] = (f32x4){0.f, 0.f, 0.f, 0.f};

    for (int k0 = 0; k0 < K; k0 += 32) {
        gload16(Ag + k0, Alds);
        gload16(Bg + k0, Blds);
        __syncthreads();
        bf16x8 af[2], bfr[2];
        #pragma unroll
        for (int mt = 0; mt < 2; mt++) {
            int ar = wr * 32 + mt * 16 + l15;
            af[mt] = *(const bf16x8*)&As[SWZ(ar, quad)];
        }
        #pragma unroll
        for (int nt = 0; nt < 2; nt++) {
            int br = wc * 32 + nt * 16 + l15;
            bfr[nt] = *(const bf16x8*)&Bs[SWZ(br, quad)];
        }
        #pragma unroll
        for (int mt = 0; mt < 2; mt++)
            #pragma unroll
            for (int nt = 0; nt < 2; nt++)
                acc[mt][nt] = __builtin_amdgcn_mfma_f32_16x16x32_bf16(
                    af[mt], bfr[nt], acc[mt][nt], 0, 0, 0);
        __syncthreads();
    }

    #pragma unroll
    for (int mt = 0; mt < 2; mt++) {
        #pragma unroll
        for (int nt = 0; nt < 2; nt++) {
            #pragma unroll
            for (int reg = 0; reg < 4; reg++) {
                int gr = row0 + wr * 32 + mt * 16 + quad * 4 + reg;
                int gc = col0 + wc * 32 + nt * 16 + l15;
                float x = acc[mt][nt][reg] + xb0[gc];
                if (EPI == GEPI_IS0) {
                    size_t srow = (size_t)gr * 8 + (gc >> 8);
                    int dim = gc & 255;
                    fp0[srow * 256 + dim] = x;                      // slots f32
                    ushort xb = f2bu(x);
                    up0[srow * 512 + dim]       = xb;               // catb is0
                    up0[srow * 512 + 256 + dim] = xb;               // catb slot
                } else if (EPI == GEPI_RELU) {
                    up0[(size_t)gr * 512 + gc] = f2bu(fmaxf(x, 0.f)); // hbuf
                } else if (EPI == GEPI_MLP2 || EPI == GEPI_MLP2L) {
                    size_t i = (size_t)gr * 256 + gc;
                    float s = fp0[i] + x * (1.f / 256.f);
                    if (EPI == GEPI_MLP2) fp0[i] = s;               // dead on last iter
                    up0[(size_t)gr * 512 + 256 + gc] = f2bu(s);     // catb slot
                } else {  // GEPI_OUT
                    fp0[(size_t)gr * 256 + gc] = x;                 // out f32
                }
            }
        }
    }
}

// ---- KV GEMM: 64x64 tiles, bf16 A pre-converted by prep, gload_lds staging.
__global__ __launch_bounds__(256) void gemm_kv64(
    const ushort* __restrict__ A0,   // sentence bf16, rows 0..32767
    const ushort* __restrict__ A1,   // sentence bf16, rows 32768..49151
    const ushort* __restrict__ Bt,
    const float* __restrict__ bk, const float* __restrict__ bv,
    ushort* __restrict__ kbuf, ushort* __restrict__ vbuf, int K)
{
    __shared__ ushort As[64 * 32];
    __shared__ ushort Bs[64 * 32];
    int tid = threadIdx.x;
    int wave = tid >> 6, lane = tid & 63;
    int wr = wave >> 1, wc = wave & 1;
    int quad = lane >> 4, l15 = lane & 15;

    int bid = blockIdx.x;
    int x8  = bid & 7;
    int tt  = bid >> 3;            // 0..767
    int cb  = tt & 7;
    int rb  = (tt >> 3) * 8 + x8;  // 0..767, bijective
    int row0 = rb * 64, col0 = cb * 64;

    int r   = (wave << 4) + (lane >> 2);
    int csw = ((((lane & 3) ^ (r >> 1)) & 3) << 3);
    ushort* Alds = &As[wave << 9];
    ushort* Blds = &Bs[wave << 9];
    const ushort* Ag = (row0 < 32768)
        ? (A0 + (size_t)(row0 + r) * K + csw)
        : (A1 + (size_t)(row0 - 32768 + r) * K + csw);
    const ushort* Bg = Bt + (size_t)(col0 + r) * K + csw;

    f32x4 acc[2][2];
    #pragma unroll
    for (int i = 0; i < 2; i++)
        #pragma unroll
        for (int j = 0; j < 2; j++) acc[i][j] = (f32x4){0.f, 0.f, 0.f, 0.f};

    for (int k0 = 0; k0 < K; k0 += 32) {
        gload16(Ag + k0, Alds);
        gload16(Bg + k0, Blds);
        __syncthreads();
        bf16x8 af[2], bfr[2];
        #pragma unroll
        for (int mt = 0; mt < 2; mt++) {
            int ar = wr * 32 + mt * 16 + l15;
            af[mt] = *(const bf16x8*)&As[SWZ(ar, quad)];
        }
        #pragma unroll
        for (int nt = 0; nt < 2; nt++) {
            int br = wc * 32 + nt * 16 + l15;
            bfr[nt] = *(const bf16x8*)&Bs[SWZ(br, quad)];
        }
        #pragma unroll
        for (int mt = 0; mt < 2; mt++)
            #pragma unroll
            for (int nt = 0; nt < 2; nt++)
                acc[mt][nt] = __builtin_amdgcn_mfma_f32_16x16x32_bf16(
                    af[mt], bfr[nt], acc[mt][nt], 0, 0, 0);
        __syncthreads();
    }

    bool isK = (col0 < 256);
    const float* __restrict__ bias = isK ? bk : bv;
    ushort* __restrict__ outp = isK ? kbuf : vbuf;
    int cbase = isK ? col0 : col0 - 256;

    #pragma unroll
    for (int mt = 0; mt < 2; mt++) {
        #pragma unroll
        for (int nt = 0; nt < 2; nt++) {
            #pragma unroll
            for (int reg = 0; reg < 4; reg++) {
                int gr = row0 + wr * 32 + mt * 16 + quad * 4 + reg;
                int gc = cbase + wc * 32 + nt * 16 + l15;
                float x = acc[mt][nt][reg] + bias[gc];
                if (isK) x = x > 0.f ? x + 1.f : expf(x);
                outp[(size_t)gr * 256 + gc] = f2bu(x);
            }
        }
    }
}

// sentence -> bf16 (split aliased regions) + ssum -> bf16 + weights -> bf16^T.
__global__ __launch_bounds__(256) void prep_kernel(
    const float* __restrict__ sentence,
    const float* __restrict__ sent_sum,
    const float* __restrict__ Wbind, const float* __restrict__ Wk,
    const float* __restrict__ Wv, const float* __restrict__ Wq,
    const float* __restrict__ W1, const float* __restrict__ W2,
    const float* __restrict__ Wproj,
    ushort* __restrict__ sentA0, ushort* __restrict__ sentA1,
    ushort* __restrict__ ssum_bf,
    ushort* __restrict__ Wbind_t, ushort* __restrict__ Wkv_t,
    ushort* __restrict__ Wq_t, ushort* __restrict__ W1_t,
    ushort* __restrict__ W2_t, ushort* __restrict__ Wproj_t)
{
    int gid = blockIdx.x * 256 + threadIdx.x;
    if (gid < 6291456) {           // sentence: 25,165,824 f32 as vec4
        float4 f = ((const float4*)sentence)[gid];
        uint2 o; o.x = cvtpk2(f.x, f.y); o.y = cvtpk2(f.z, f.w);
        if (gid < 4194304) ((uint2*)sentA0)[gid] = o;        // rows 0..32767
        else               ((uint2*)sentA1)[gid - 4194304] = o; // rows 32768..
        return;
    }
    int idx = gid - 6291456;
    if (idx < 262144) {            // sent_sum: 1,048,576 f32 as vec4
        float4 f = ((const float4*)sent_sum)[idx];
        uint2 o; o.x = pack2(f.x, f.y); o.y = pack2(f.z, f.w);
        ((uint2*)ssum_bf)[idx] = o; return;
    }
    idx -= 262144;
    if (idx < 1048576) { int n = idx >> 9, k = idx & 511;
        Wbind_t[idx] = f2bu(Wbind[(size_t)k * 2048 + n]); return; }
    idx -= 1048576;
    if (idx < 262144) { int n = idx >> 9, k = idx & 511;
        Wkv_t[idx] = f2bu(n < 256 ? Wk[(size_t)k * 256 + n] : Wv[(size_t)k * 256 + n - 256]); return; }
    idx -= 262144;
    if (idx < 65536) { int n = idx >> 8, k = idx & 255;
        Wq_t[idx] = f2bu(Wq[(size_t)k * 256 + n]); return; }
    idx -= 65536;
    if (idx < 131072) { int n = idx >> 8, k = idx & 255;
        W1_t[idx] = f2bu(W1[(size_t)k * 512 + n]); return; }
    idx -= 131072;
    if (idx < 131072) { int n = idx >> 9, k = idx & 511;
        W2_t[idx] = f2bu(W2[(size_t)k * 256 + n]); return; }
    idx -= 131072;
    if (idx < 131072) { int n = idx >> 9, k = idx & 511;
        Wproj_t[idx] = f2bu(Wproj[(size_t)k * 256 + n]); return; }
}

// Per-(n,b): q (fused MFMA, bit-identical to the old Q-gemm) -> logits ->
// softmax(+eps) -> word renorm -> update -> LayerNorm.
// vv is NOT staged (each element read once -> direct global reads).
// The q A-tile LDS region is reused for `us` after the q phase (time-disjoint).
__global__ __launch_bounds__(256) void attn_kernel(
    const ushort* __restrict__ kbuf, const ushort* __restrict__ vbuf,
    const ushort* __restrict__ catb,   // [16384,512] = [is0|slot] bf16
    const ushort* __restrict__ Wqt,    // [256,256] bf16 [N,K]
    const float*  __restrict__ bq,
    const int* __restrict__ mask,
    const float* __restrict__ g_ln, const float* __restrict__ b_ln,
    ushort* __restrict__ ubuf)
{
    const int W = 24, S = 8;
    __shared__ ushort kk[24 * 264], qsb[8 * 264];
    __shared__ __align__(16) float us[8 * 257];   // q-phase: aliased as uQ tiles
    __shared__ float attnw[24][8];
    __shared__ float colsum[8], mean_s[8], rstd_s[8], maskf[24];
    ushort* uQ = (ushort*)us;                     // [8 kc][16x32 SWZ tile]

    int nb = blockIdx.x, t = threadIdx.x;
    int wave = t >> 6, lane = t & 63;
    int quad = lane >> 4, l15 = lane & 15;
    size_t bw = (size_t)nb * W * 256, bs = (size_t)nb * S * 256;

    for (int l = t; l < 3072; l += 256) {         // kk rows read 8x -> stage
        int row = l >> 7, col = l & 127;
        ((uint*)kk)[row * 132 + col] = ((const uint*)(kbuf + bw))[l];
    }
    {   // stage catb slot rows (8 valid + 8 zero) into SWZ k-tiles (MFMA A)
        int r = t >> 4, cc = t & 15;              // 16 rows x 16 chunks of 8
        uint4 v = (uint4){0u, 0u, 0u, 0u};
        if (r < 8) v = *(const uint4*)(catb + (size_t)(nb * 8 + r) * 512 + 256 + cc * 8);
        *(uint4*)&uQ[(cc >> 2) * 512 + SWZ(r, cc & 3)] = v;
    }
    if (t < W) maskf[t] = mask[(size_t)nb * W + t] ? 0.f : -1e6f;
    __syncthreads();

    // q = elu((slot @ Wq + bq + is0) * 0.0625) + 1 -> qsb (bf16).
    // Same MFMA, same K-order, same inputs as the old gemm64<Q> -> bit-identical.
    {
        f32x4 qa[4];
        #pragma unroll
        for (int i = 0; i < 4; i++) qa[i] = (f32x4){0.f, 0.f, 0.f, 0.f};
        #pragma unroll
        for (int kc = 0; kc < 8; kc++) {
            bf16x8 a = *(const bf16x8*)&uQ[kc * 512 + SWZ(l15, quad)];
            #pragma unroll
            for (int ct = 0; ct < 4; ct++) {
                int n = wave * 64 + ct * 16 + l15;
                bf16x8 b = *(const bf16x8*)(Wqt + (size_t)n * 256 + kc * 32 + quad * 8);
                qa[ct] = __builtin_amdgcn_mfma_f32_16x16x32_bf16(a, b, qa[ct], 0, 0, 0);
            }
        }
        __syncthreads();    // all uQ reads done before us overwrite later; also
                            // ensures qsb writes below are not racing stale uQ use
        #pragma unroll
        for (int ct = 0; ct < 4; ct++) {
            int col = wave * 64 + ct * 16 + l15;
            #pragma unroll
            for (int reg = 0; reg < 4; reg++) {
                int row = quad * 4 + reg;
                if (row < 8) {
                    float x = qa[ct][reg] + bq[col]
                            + bu2f(catb[(size_t)(nb * 8 + row) * 512 + col]);
                    float y = x * 0.0625f;
                    y = y > 0.f ? y + 1.f : expf(y);
                    qsb[row * 264 + col] = f2bu(y);
                }
            }
        }
    }
    __syncthreads();

    if (t < W * S) {
        int i = t >> 3, j = t & 7;
        float a = 0.f;
        for (int d0 = 0; d0 < 256; d0 += 8) {
            bf16x8 kv8 = *(const bf16x8*)&kk[i * 264 + d0];
            bf16x8 qv8 = *(const bf16x8*)&qsb[j * 264 + d0];
            #pragma unroll
            for (int m = 0; m < 8; m++)
                a += bu2f((ushort)kv8[m]) * bu2f((ushort)qv8[m]);
        }
        attnw[i][j] = a + maskf[i];
    }
    __syncthreads();

    if (t < W) {
        float m = attnw[t][0];
        #pragma unroll
        for (int j = 1; j < S; j++) m = fmaxf(m, attnw[t][j]);
        float e[S]; float s = 0.f;
        #pragma unroll
        for (int j = 0; j < S; j++) { e[j] = expf(attnw[t][j] - m); s += e[j]; }
        #pragma unroll
        for (int j = 0; j < S; j++) attnw[t][j] = e[j] / s + 1e-6f;
    }
    __syncthreads();

    if (t < S) {
        float s = 0.f;
        for (int i = 0; i < W; i++) s += attnw[i][t];
        colsum[t] = s;
    }
    __syncthreads();

    {
        float acc[S] = {};
        #pragma unroll
        for (int i = 0; i < W; i++) {
            float vx = bu2f(vbuf[bw + (size_t)i * 256 + t]);   // direct global
            float4 w0 = *(const float4*)&attnw[i][0];
            float4 w1 = *(const float4*)&attnw[i][4];
            acc[0] += w0.x * vx; acc[1] += w0.y * vx;
            acc[2] += w0.z * vx; acc[3] += w0.w * vx;
            acc[4] += w1.x * vx; acc[5] += w1.y * vx;
            acc[6] += w1.z * vx; acc[7] += w1.w * vx;
        }
        #pragma unroll
        for (int j = 0; j < S; j++) us[j * 257 + t] = acc[j] / colsum[j];
    }
    __syncthreads();

    {
        int l63 = t & 63;
        #pragma unroll
        for (int jj = 0; jj < 2; jj++) {
            int j = (t >> 6) * 2 + jj;
            float x0 = us[j * 257 + l63],       x1 = us[j * 257 + l63 + 64];
            float x2 = us[j * 257 + l63 + 128], x3 = us[j * 257 + l63 + 192];
            float p = x0 + x1 + x2 + x3;
            for (int off = 32; off; off >>= 1) p += __shfl_xor(p, off);
            float mean = p * (1.f / 256.f);
            float d0 = x0 - mean, d1 = x1 - mean, d2 = x2 - mean, d3 = x3 - mean;
            float vr = d0 * d0 + d1 * d1 + d2 * d2 + d3 * d3;
            for (int off = 32; off; off >>= 1) vr += __shfl_xor(vr, off);
            if (l63 == 0) {
                mean_s[j] = mean;
                rstd_s[j] = rsqrtf(vr * (1.f / 256.f) + 1e-5f);
            }
        }
    }
    __syncthreads();

    {
        float g = g_ln[t], bb = b_ln[t];
        #pragma unroll
        for (int j = 0; j < S; j++)
            ubuf[bs + j * 256 + t] = f2bu((us[j * 257 + t] - mean_s[j]) * rstd_s[j] * g + bb);
    }
}

// ---------------- fallback: round-4 proven mega-kernel ----------------
__global__ __launch_bounds__(256) void mega_kernel(
    const float* __restrict__ sentence, const float* __restrict__ sent_sum,
    const int*  __restrict__ mask,
    const float* __restrict__ Wk, const float* __restrict__ bk,
    const float* __restrict__ Wv, const float* __restrict__ bv,
    const float* __restrict__ Wq, const float* __restrict__ bq,
    const float* __restrict__ g_ln, const float* __restrict__ b_ln,
    const float* __restrict__ W1, const float* __restrict__ b1,
    const float* __restrict__ W2, const float* __restrict__ b2,
    const float* __restrict__ Wbind, const float* __restrict__ bbind,
    const float* __restrict__ Wproj, const float* __restrict__ bproj,
    float* __restrict__ out)
{
    const int W = 24, S = 8, D = 256, IN = 512, H = 512;
    __shared__ float seh[2048];
    __shared__ ushort kk[24 * 256];
    __shared__ ushort vv[24 * 256];
    __shared__ float is0s[8 * 256];
    __shared__ float sl[8 * 256];
    __shared__ float qv[8 * 256];
    __shared__ float attnw[24][8];
    __shared__ float colsum[8], mean_s[8], rstd_s[8], maskf[24];

    int nb = blockIdx.x, t = threadIdx.x;
    size_t sbase = (size_t)nb * W * IN;

    if (t < W) maskf[t] = mask[(size_t)nb * W + t] ? 0.f : -1e6f;
    for (int l = t; l < IN; l += 256) seh[l] = sent_sum[(size_t)nb * IN + l];
    __syncthreads();
    {
        float acc[S];
        #pragma unroll
        for (int j = 0; j < S; j++) acc[j] = bbind[j * D + t];
        for (int c = 0; c < IN; c++) {
            float sc = seh[c];
            #pragma unroll
            for (int j = 0; j < S; j++) acc[j] += sc * Wbind[(size_t)c * (S * D) + j * D + t];
        }
        #pragma unroll
        for (int j = 0; j < S; j++) { is0s[j * D + t] = acc[j]; sl[j * D + t] = acc[j]; }
    }
    {
        float ka[W], va[W];
        float bkv = bk[t], bvv = bv[t];
        #pragma unroll
        for (int i = 0; i < W; i++) { ka[i] = bkv; va[i] = bvv; }
        for (int ch = 0; ch < 8; ch++) {
            __syncthreads();
            for (int l = t; l < W * 64; l += 256) {
                int i = l >> 6, c = l & 63;
                seh[l] = sentence[sbase + (size_t)i * IN + ch * 64 + c];
            }
            __syncthreads();
            for (int c = 0; c < 64; c++) {
                int cg = ch * 64 + c;
                float wk = Wk[(size_t)cg * D + t];
                float wv = Wv[(size_t)cg * D + t];
                #pragma unroll
                for (int i = 0; i < W; i++) {
                    float s = seh[i * 64 + c];
                    ka[i] += s * wk; va[i] += s * wv;
                }
            }
        }
        #pragma unroll
        for (int i = 0; i < W; i++) {
            float kx = ka[i];
            kk[i * D + t] = f2bu(kx > 0.f ? kx + 1.f : expf(kx));
            vv[i * D + t] = f2bu(va[i]);
        }
    }
    __syncthreads();

    for (int it = 0; it < 3; it++) {
        {
            float qa[S]; float bqv = bq[t];
            #pragma unroll
            for (int j = 0; j < S; j++) qa[j] = bqv + is0s[j * D + t];
            for (int c = 0; c < D; c++) {
                float wq = Wq[(size_t)c * D + t];
                #pragma unroll
                for (int j = 0; j < S; j++) qa[j] += sl[j * D + c] * wq;
            }
            #pragma unroll
            for (int j = 0; j < S; j++) {
                float y = qa[j] * 0.0625f;
                qv[j * D + t] = y > 0.f ? y + 1.f : expf(y);
            }
        }
        __syncthreads();
        if (t < W * S) {
            int i = t >> 3, j = t & 7;
            float a = 0.f;
            #pragma unroll 8
            for (int d = 0; d < D; d++) a += bu2f(kk[i * D + d]) * qv[j * D + d];
            attnw[i][j] = a + maskf[i];
        }
        __syncthreads();
        if (t < W) {
            float m = attnw[t][0];
            #pragma unroll
            for (int j = 1; j < S; j++) m = fmaxf(m, attnw[t][j]);
            float e[S]; float s = 0.f;
            #pragma unroll
            for (int j = 0; j < S; j++) { e[j] = expf(attnw[t][j] - m); s += e[j]; }
            #pragma unroll
            for (int j = 0; j < S; j++) attnw[t][j] = e[j] / s + 1e-6f;
        }
        __syncthreads();
        if (t < S) {
            float s = 0.f;
            for (int i = 0; i < W; i++) s += attnw[i][t];
            colsum[t] = s;
        }
        __syncthreads();
        {
            float acc[S] = {};
            #pragma unroll
            for (int i = 0; i < W; i++) {
                float vx = bu2f(vv[i * D + t]);
                #pragma unroll
                for (int j = 0; j < S; j++) acc[j] += attnw[i][j] * vx;
            }
            #pragma unroll
            for (int j = 0; j < S; j++) qv[j * D + t] = acc[j] / colsum[j];
        }
        __syncthreads();
        {
            int lane = t & 63;
            #pragma unroll
            for (int jj = 0; jj < 2; jj++) {
                int j = (t >> 6) * 2 + jj;
                float x0 = qv[j * D + lane],       x1 = qv[j * D + lane + 64];
                float x2 = qv[j * D + lane + 128], x3 = qv[j * D + lane + 192];
                float p = x0 + x1 + x2 + x3;
                for (int off = 32; off; off >>= 1) p += __shfl_xor(p, off);
                float mean = p * (1.f / 256.f);
                float d0 = x0 - mean, d1 = x1 - mean, d2 = x2 - mean, d3 = x3 - mean;
                float vr = d0 * d0 + d1 * d1 + d2 * d2 + d3 * d3;
                for (int off = 32; off; off >>= 1) vr += __shfl_xor(vr, off);
                if (lane == 0) { mean_s[j] = mean; rstd_s[j] = rsqrtf(vr * (1.f / 256.f) + 1e-5f); }
            }
        }
        __syncthreads();
        {
            float g = g_ln[t], bb = b_ln[t];
            #pragma unroll
            for (int j = 0; j < S; j++)
                qv[j * D + t] = (qv[j * D + t] - mean_s[j]) * rstd_s[j] * g + bb;
        }
        __syncthreads();
        {
            float sa[S]; float b2v = b2[t];
            #pragma unroll
            for (int j = 0; j < S; j++) sa[j] = b2v;
            for (int half = 0; half < 2; half++) {
                int hcol = half * 256 + t;
                float ha[S]; float b1v = b1[hcol];
                #pragma unroll
                for (int j = 0; j < S; j++) ha[j] = b1v;
                for (int d = 0; d < D; d++) {
                    float w1 = W1[(size_t)d * H + hcol];
                    #pragma unroll
                    for (int j = 0; j < S; j++) ha[j] += qv[j * D + d] * w1;
                }
                __syncthreads();
                #pragma unroll
                for (int j = 0; j < S; j++) seh[j * D + t] = fmaxf(ha[j], 0.f);
                __syncthreads();
                for (int h = 0; h < 256; h++) {
                    float w2 = W2[(size_t)(half * 256 + h) * D + t];
                    #pragma unroll
                    for (int j = 0; j < S; j++) sa[j] += seh[j * D + h] * w2;
                }
            }
            __syncthreads();
            #pragma unroll
            for (int j = 0; j < S; j++) sl[j * D + t] += sa[j] * (1.f / 256.f);
        }
        __syncthreads();
    }
    {
        float oa[S]; float bpv = bproj[t];
        #pragma unroll
        for (int j = 0; j < S; j++) oa[j] = bpv;
        for (int c = 0; c < D; c++) {
            float wp1 = Wproj[(size_t)c * D + t];
            float wp2 = Wproj[(size_t)(D + c) * D + t];
            #pragma unroll
            for (int j = 0; j < S; j++)
                oa[j] += is0s[j * D + c] * wp1 + sl[j * D + c] * wp2;
        }
        #pragma unroll
        for (int j = 0; j < S; j++)
            out[(size_t)nb * (S * D) + j * D + t] = oa[j];
    }
}

extern "C" void kernel_launch(void* const* d_in, const int* in_sizes, int n_in,
                              void* d_out, int out_size, void* d_ws, size_t ws_size,
                              hipStream_t stream)
{
    const float* sentence = (const float*)d_in[0];
    const float* sent_sum = (const float*)d_in[1];
    const int*  mask      = (const int*)d_in[2];
    const float* Wk = (const float*)d_in[3];  const float* bk = (const float*)d_in[4];
    const float* Wv = (const float*)d_in[5];  const float* bv = (const float*)d_in[6];
    const float* Wq = (const float*)d_in[7];  const float* bq = (const float*)d_in[8];
    const float* g_ln = (const float*)d_in[9];  const float* b_ln = (const float*)d_in[10];
    const float* W1 = (const float*)d_in[11]; const float* b1 = (const float*)d_in[12];
    const float* W2 = (const float*)d_in[13]; const float* b2 = (const float*)d_in[14];
    const float* Wbind = (const float*)d_in[15]; const float* bbind = (const float*)d_in[16];
    const float* Wproj = (const float*)d_in[17]; const float* bproj = (const float*)d_in[18];
    float* out = (float*)d_out;

    const size_t WS_NEEDED = 123076608ULL;
    if (ws_size >= WS_NEEDED) {
        char* w = (char*)d_ws;
        float*  slots   = (float*) (w);                 // 16 MB  [16384,256] f32
        ushort* catb    = (ushort*)(w + 16777216);      // 16 MB  [16384,512] = [is0|slots] bf16
        ushort* kbuf    = (ushort*)(w + 33554432);      // 24 MB  [49152,256]
        ushort* vbuf    = (ushort*)(w + 58720256);      // 24 MB
        ushort* ubuf    = (ushort*)(w + 92274688);      //  8 MB
        ushort* hbuf    = (ushort*)(w + 100663296);     // 16 MB  [16384,512]
        ushort* ssum_bf = (ushort*)(w + 117440512);     //  2 MB
        ushort* Wbind_t = (ushort*)(w + 119537664);
        ushort* Wkv_t   = (ushort*)(w + 121634816);
        ushort* Wq_t    = (ushort*)(w + 122159104);
        ushort* W1_t    = (ushort*)(w + 122290176);
        ushort* W2_t    = (ushort*)(w + 122552320);
        ushort* Wproj_t = (ushort*)(w + 122814464);

        // sentence-bf16 lives in regions that are dead until after gemm_kv64:
        //   rows 0..32767  -> slots+catb   (32 MB; first written by gemm64<IS0>)
        //   rows 32768..   -> old-qbuf+ubuf (16 MB; ubuf first written in iter 1)
        ushort* sentA0 = (ushort*)(w);
        ushort* sentA1 = (ushort*)(w + 83886080);

        prep_kernel<<<dim3(32512), dim3(256), 0, stream>>>(
            sentence, sent_sum, Wbind, Wk, Wv, Wq, W1, W2, Wproj,
            sentA0, sentA1,
            ssum_bf, Wbind_t, Wkv_t, Wq_t, W1_t, W2_t, Wproj_t);

        gemm_kv64<<<dim3(6144), dim3(256), 0, stream>>>(
            sentA0, sentA1, Wkv_t, bk, bv, kbuf, vbuf, 512);

        // is0 = ssum @ Wbind + bbind -> slots f32 + both catb halves
        gemm64<GEPI_IS0, 32><<<dim3(1024), dim3(256), 0, stream>>>(
            ssum_bf, 512, Wbind_t, bbind,
            slots, catb, nullptr, 2048, 2048, 512);

        for (int it = 0; it < 3; it++) {
            attn_kernel<<<dim3(2048), dim3(256), 0, stream>>>(
                kbuf, vbuf, catb, Wq_t, bq, mask, g_ln, b_ln, ubuf);
            gemm64<GEPI_RELU, 8><<<dim3(2048), dim3(256), 0, stream>>>(
                ubuf, 256, W1_t, b1,
                nullptr, hbuf, nullptr, 16384, 512, 256);
            if (it < 2)
                gemm64<GEPI_MLP2, 4><<<dim3(1024), dim3(256), 0, stream>>>(
                    hbuf, 512, W2_t, b2,
                    slots, catb, nullptr, 16384, 256, 512);
            else
                gemm64<GEPI_MLP2L, 4><<<dim3(1024), dim3(256), 0, stream>>>(
                    hbuf, 512, W2_t, b2,
                    slots, catb, nullptr, 16384, 256, 512);
        }

        gemm64<GEPI_OUT, 4><<<dim3(1024), dim3(256), 0, stream>>>(
            catb, 512, Wproj_t, bproj,
            out, nullptr, nullptr, 16384, 256, 512);
    } else {
        mega_kernel<<<dim3(2048), dim3(256), 0, stream>>>(
            sentence, sent_sum, mask, Wk, bk, Wv, bv, Wq, bq, g_ln, b_ln,
            W1, b1, W2, b2, Wbind, bbind, Wproj, bproj, out);
    }
}

// Round 13
// 433.291 us; speedup vs baseline: 1.2088x; 1.2088x over previous
//
#include <hip/hip_runtime.h>
#include <hip/hip_bf16.h>
#include <math.h>

typedef unsigned int uint;
typedef unsigned short ushort;
typedef __attribute__((ext_vector_type(8))) short bf16x8;
typedef __attribute__((ext_vector_type(4))) float f32x4;

__device__ __forceinline__ float bu2f(ushort u){ union{uint u; float f;} v; v.u = ((uint)u)<<16; return v.f; }
__device__ __forceinline__ ushort f2bu(float x){ union{float f; uint u;} v; v.f = x; uint r = (v.u + 0x7FFFu + ((v.u>>16)&1u))>>16; return (ushort)r; }
__device__ __forceinline__ uint pack2(float a, float b){ return (uint)f2bu(a) | ((uint)f2bu(b) << 16); }
// HW packed f32->bf16 (RNE, bit-identical to f2bu for non-NaN), 1 VALU op. [gfx950]
__device__ __forceinline__ uint cvtpk2(float a, float b){
    uint r; asm("v_cvt_pk_bf16_f32 %0, %1, %2" : "=v"(r) : "v"(a), "v"(b)); return r;
}
// Async global->LDS DMA, 16B/lane: dest = wave-uniform LDS base + lane*16.
__device__ __forceinline__ void gload16(const ushort* g, ushort* l){
    __builtin_amdgcn_global_load_lds(
        (const __attribute__((address_space(1))) uint*)g,
        (__attribute__((address_space(3))) uint*)l, 16, 0, 0);
}

#define GEPI_IS0   0
#define GEPI_Q     2
#define GEPI_RELU  3
#define GEPI_MLP2  4
#define GEPI_OUT   5
#define GEPI_MLP2L 6   // last-iter MLP2: slots f32 is dead afterwards -> skip store

// LDS tile: [R][32] ushorts, NO pad; 16B chunk c of row r stored at slot
// (c ^ (r>>1))&3.  Conflict-free on both sides (verified: 0 conflicts).
#define SWZ(r, c) (((r) << 5) + ((((c) ^ ((r) >> 1)) & 3) << 3))

// ---- small-GEMM: 64x64 tile, 4 waves (2x2) of 32x32, gload_lds staging,
//      DOUBLE-BUFFERED K-loop: two 32-K subtiles per barrier pair (halves the
//      number of barrier-drain events -- the measured binder; accumulation
//      order unchanged -> bit-identical).  1D grid, bijective XCD swizzle.
template<int EPI, int CB>
__global__ __launch_bounds__(256) void gemm64(
    const ushort* __restrict__ Abf, int lda,
    const ushort* __restrict__ Bt,
    const float* __restrict__ xb0,
    float* __restrict__ fp0,
    ushort* __restrict__ up0, ushort* __restrict__ up1,
    int M, int N, int K)
{
    __shared__ ushort As[2][64 * 32];
    __shared__ ushort Bs[2][64 * 32];
    int tid = threadIdx.x;
    int wave = tid >> 6, lane = tid & 63;
    int wr = wave >> 1, wc = wave & 1;
    int quad = lane >> 4, l15 = lane & 15;

    constexpr int LCB = (CB == 4) ? 2 : (CB == 8) ? 3 : 5;   // log2(CB): 4,8,32
    int bid = blockIdx.x;
    int x8  = bid & 7;
    int tt  = bid >> 3;
    int cb  = tt & (CB - 1);
    int rb  = ((tt >> LCB) << 3) + x8;     // bijective
    int row0 = rb * 64, col0 = cb * 64;

    int r   = (wave << 4) + (lane >> 2);
    int csw = ((((lane & 3) ^ (r >> 1)) & 3) << 3);
    const ushort* Ag = Abf + (size_t)(row0 + r) * lda + csw;
    const ushort* Bg = Bt  + (size_t)(col0 + r) * K   + csw;

    f32x4 acc[2][2];
    #pragma unroll
    for (int i = 0; i < 2; i++)
        #pragma unroll
        for (int j = 0; j < 2; j++) acc[i][j] = (f32x4){0.f, 0.f, 0.f, 0.f};

    for (int k0 = 0; k0 < K; k0 += 64) {
        gload16(Ag + k0,      &As[0][wave << 9]);
        gload16(Bg + k0,      &Bs[0][wave << 9]);
        gload16(Ag + k0 + 32, &As[1][wave << 9]);
        gload16(Bg + k0 + 32, &Bs[1][wave << 9]);
        __syncthreads();               // vmcnt(0) drain -> DMA data visible
        #pragma unroll
        for (int b = 0; b < 2; b++) {
            bf16x8 af[2], bfr[2];
            #pragma unroll
            for (int mt = 0; mt < 2; mt++) {
                int ar = wr * 32 + mt * 16 + l15;
                af[mt] = *(const bf16x8*)&As[b][SWZ(ar, quad)];
            }
            #pragma unroll
            for (int nt = 0; nt < 2; nt++) {
                int br = wc * 32 + nt * 16 + l15;
                bfr[nt] = *(const bf16x8*)&Bs[b][SWZ(br, quad)];
            }
            #pragma unroll
            for (int mt = 0; mt < 2; mt++)
                #pragma unroll
                for (int nt = 0; nt < 2; nt++)
                    acc[mt][nt] = __builtin_amdgcn_mfma_f32_16x16x32_bf16(
                        af[mt], bfr[nt], acc[mt][nt], 0, 0, 0);
        }
        __syncthreads();               // reads done before next DMA overwrites
    }

    #pragma unroll
    for (int mt = 0; mt < 2; mt++) {
        #pragma unroll
        for (int nt = 0; nt < 2; nt++) {
            #pragma unroll
            for (int reg = 0; reg < 4; reg++) {
                int gr = row0 + wr * 32 + mt * 16 + quad * 4 + reg;
                int gc = col0 + wc * 32 + nt * 16 + l15;
                float x = acc[mt][nt][reg] + xb0[gc];
                if (EPI == GEPI_IS0) {
                    size_t srow = (size_t)gr * 8 + (gc >> 8);
                    int dim = gc & 255;
                    fp0[srow * 256 + dim] = x;                      // slots f32
                    ushort xb = f2bu(x);
                    up0[srow * 512 + dim]       = xb;               // catb is0
                    up0[srow * 512 + 256 + dim] = xb;               // catb slot
                } else if (EPI == GEPI_Q) {
                    float y = (x + bu2f(up1[(size_t)gr * 512 + gc])) * 0.0625f;
                    y = y > 0.f ? y + 1.f : expf(y);
                    up0[(size_t)gr * 256 + gc] = f2bu(y);           // qbuf bf16
                } else if (EPI == GEPI_RELU) {
                    up0[(size_t)gr * 512 + gc] = f2bu(fmaxf(x, 0.f)); // hbuf
                } else if (EPI == GEPI_MLP2 || EPI == GEPI_MLP2L) {
                    size_t i = (size_t)gr * 256 + gc;
                    float s = fp0[i] + x * (1.f / 256.f);
                    if (EPI == GEPI_MLP2) fp0[i] = s;               // dead on last iter
                    up0[(size_t)gr * 512 + 256 + gc] = f2bu(s);     // catb slot
                } else {  // GEPI_OUT
                    fp0[(size_t)gr * 256 + gc] = x;                 // out f32
                }
            }
        }
    }
}

// ---- KV GEMM: 64x64 tiles, bf16 A pre-converted by prep, gload_lds staging,
//      double-buffered K-loop (same mechanics as gemm64).
__global__ __launch_bounds__(256) void gemm_kv64(
    const ushort* __restrict__ A0,   // sentence bf16, rows 0..32767
    const ushort* __restrict__ A1,   // sentence bf16, rows 32768..49151
    const ushort* __restrict__ Bt,
    const float* __restrict__ bk, const float* __restrict__ bv,
    ushort* __restrict__ kbuf, ushort* __restrict__ vbuf, int K)
{
    __shared__ ushort As[2][64 * 32];
    __shared__ ushort Bs[2][64 * 32];
    int tid = threadIdx.x;
    int wave = tid >> 6, lane = tid & 63;
    int wr = wave >> 1, wc = wave & 1;
    int quad = lane >> 4, l15 = lane & 15;

    int bid = blockIdx.x;
    int x8  = bid & 7;
    int tt  = bid >> 3;            // 0..767
    int cb  = tt & 7;
    int rb  = (tt >> 3) * 8 + x8;  // 0..767, bijective
    int row0 = rb * 64, col0 = cb * 64;

    int r   = (wave << 4) + (lane >> 2);
    int csw = ((((lane & 3) ^ (r >> 1)) & 3) << 3);
    const ushort* Ag = (row0 < 32768)
        ? (A0 + (size_t)(row0 + r) * K + csw)
        : (A1 + (size_t)(row0 - 32768 + r) * K + csw);
    const ushort* Bg = Bt + (size_t)(col0 + r) * K + csw;

    f32x4 acc[2][2];
    #pragma unroll
    for (int i = 0; i < 2; i++)
        #pragma unroll
        for (int j = 0; j < 2; j++) acc[i][j] = (f32x4){0.f, 0.f, 0.f, 0.f};

    for (int k0 = 0; k0 < K; k0 += 64) {
        gload16(Ag + k0,      &As[0][wave << 9]);
        gload16(Bg + k0,      &Bs[0][wave << 9]);
        gload16(Ag + k0 + 32, &As[1][wave << 9]);
        gload16(Bg + k0 + 32, &Bs[1][wave << 9]);
        __syncthreads();
        #pragma unroll
        for (int b = 0; b < 2; b++) {
            bf16x8 af[2], bfr[2];
            #pragma unroll
            for (int mt = 0; mt < 2; mt++) {
                int ar = wr * 32 + mt * 16 + l15;
                af[mt] = *(const bf16x8*)&As[b][SWZ(ar, quad)];
            }
            #pragma unroll
            for (int nt = 0; nt < 2; nt++) {
                int br = wc * 32 + nt * 16 + l15;
                bfr[nt] = *(const bf16x8*)&Bs[b][SWZ(br, quad)];
            }
            #pragma unroll
            for (int mt = 0; mt < 2; mt++)
                #pragma unroll
                for (int nt = 0; nt < 2; nt++)
                    acc[mt][nt] = __builtin_amdgcn_mfma_f32_16x16x32_bf16(
                        af[mt], bfr[nt], acc[mt][nt], 0, 0, 0);
        }
        __syncthreads();
    }

    bool isK = (col0 < 256);
    const float* __restrict__ bias = isK ? bk : bv;
    ushort* __restrict__ outp = isK ? kbuf : vbuf;
    int cbase = isK ? col0 : col0 - 256;

    #pragma unroll
    for (int mt = 0; mt < 2; mt++) {
        #pragma unroll
        for (int nt = 0; nt < 2; nt++) {
            #pragma unroll
            for (int reg = 0; reg < 4; reg++) {
                int gr = row0 + wr * 32 + mt * 16 + quad * 4 + reg;
                int gc = cbase + wc * 32 + nt * 16 + l15;
                float x = acc[mt][nt][reg] + bias[gc];
                if (isK) x = x > 0.f ? x + 1.f : expf(x);
                outp[(size_t)gr * 256 + gc] = f2bu(x);
            }
        }
    }
}

// sentence -> bf16 (split aliased regions) + ssum -> bf16 + weights -> bf16^T.
__global__ __launch_bounds__(256) void prep_kernel(
    const float* __restrict__ sentence,
    const float* __restrict__ sent_sum,
    const float* __restrict__ Wbind, const float* __restrict__ Wk,
    const float* __restrict__ Wv, const float* __restrict__ Wq,
    const float* __restrict__ W1, const float* __restrict__ W2,
    const float* __restrict__ Wproj,
    ushort* __restrict__ sentA0, ushort* __restrict__ sentA1,
    ushort* __restrict__ ssum_bf,
    ushort* __restrict__ Wbind_t, ushort* __restrict__ Wkv_t,
    ushort* __restrict__ Wq_t, ushort* __restrict__ W1_t,
    ushort* __restrict__ W2_t, ushort* __restrict__ Wproj_t)
{
    int gid = blockIdx.x * 256 + threadIdx.x;
    if (gid < 6291456) {           // sentence: 25,165,824 f32 as vec4
        float4 f = ((const float4*)sentence)[gid];
        uint2 o; o.x = cvtpk2(f.x, f.y); o.y = cvtpk2(f.z, f.w);
        if (gid < 4194304) ((uint2*)sentA0)[gid] = o;        // rows 0..32767
        else               ((uint2*)sentA1)[gid - 4194304] = o; // rows 32768..
        return;
    }
    int idx = gid - 6291456;
    if (idx < 262144) {            // sent_sum: 1,048,576 f32 as vec4
        float4 f = ((const float4*)sent_sum)[idx];
        uint2 o; o.x = pack2(f.x, f.y); o.y = pack2(f.z, f.w);
        ((uint2*)ssum_bf)[idx] = o; return;
    }
    idx -= 262144;
    if (idx < 1048576) { int n = idx >> 9, k = idx & 511;
        Wbind_t[idx] = f2bu(Wbind[(size_t)k * 2048 + n]); return; }
    idx -= 1048576;
    if (idx < 262144) { int n = idx >> 9, k = idx & 511;
        Wkv_t[idx] = f2bu(n < 256 ? Wk[(size_t)k * 256 + n] : Wv[(size_t)k * 256 + n - 256]); return; }
    idx -= 262144;
    if (idx < 65536) { int n = idx >> 8, k = idx & 255;
        Wq_t[idx] = f2bu(Wq[(size_t)k * 256 + n]); return; }
    idx -= 65536;
    if (idx < 131072) { int n = idx >> 8, k = idx & 255;
        W1_t[idx] = f2bu(W1[(size_t)k * 512 + n]); return; }
    idx -= 131072;
    if (idx < 131072) { int n = idx >> 9, k = idx & 511;
        W2_t[idx] = f2bu(W2[(size_t)k * 256 + n]); return; }
    idx -= 131072;
    if (idx < 131072) { int n = idx >> 9, k = idx & 511;
        Wproj_t[idx] = f2bu(Wproj[(size_t)k * 256 + n]); return; }
}

// Per-(n,b): logits -> softmax(+eps) -> word renorm -> update -> LayerNorm.
// kk staged (read 8x/element); vv NOT staged (read once -> direct global, m169).
__global__ __launch_bounds__(256) void attn_kernel(
    const ushort* __restrict__ kbuf, const ushort* __restrict__ vbuf,
    const ushort* __restrict__ qbuf, const int* __restrict__ mask,
    const float* __restrict__ g_ln, const float* __restrict__ b_ln,
    ushort* __restrict__ ubuf)
{
    const int W = 24, S = 8;
    __shared__ ushort kk[24 * 264], qsb[8 * 264];
    __shared__ float us[8 * 257];
    __shared__ float attnw[24][8];
    __shared__ float colsum[8], mean_s[8], rstd_s[8], maskf[24];

    int nb = blockIdx.x, t = threadIdx.x;
    size_t bw = (size_t)nb * W * 256, bs = (size_t)nb * S * 256;

    for (int l = t; l < 3072; l += 256) {
        int row = l >> 7, col = l & 127;
        ((uint*)kk)[row * 132 + col] = ((const uint*)(kbuf + bw))[l];
    }
    for (int l = t; l < 1024; l += 256) {
        int row = l >> 7, col = l & 127;
        ((uint*)qsb)[row * 132 + col] = ((const uint*)(qbuf + bs))[l];
    }
    if (t < W) maskf[t] = mask[(size_t)nb * W + t] ? 0.f : -1e6f;
    __syncthreads();

    if (t < W * S) {
        int i = t >> 3, j = t & 7;
        float a = 0.f;
        for (int d0 = 0; d0 < 256; d0 += 8) {
            bf16x8 kv8 = *(const bf16x8*)&kk[i * 264 + d0];
            bf16x8 qv8 = *(const bf16x8*)&qsb[j * 264 + d0];
            #pragma unroll
            for (int m = 0; m < 8; m++)
                a += bu2f((ushort)kv8[m]) * bu2f((ushort)qv8[m]);
        }
        attnw[i][j] = a + maskf[i];
    }
    __syncthreads();

    if (t < W) {
        float m = attnw[t][0];
        #pragma unroll
        for (int j = 1; j < S; j++) m = fmaxf(m, attnw[t][j]);
        float e[S]; float s = 0.f;
        #pragma unroll
        for (int j = 0; j < S; j++) { e[j] = expf(attnw[t][j] - m); s += e[j]; }
        #pragma unroll
        for (int j = 0; j < S; j++) attnw[t][j] = e[j] / s + 1e-6f;
    }
    __syncthreads();

    if (t < S) {
        float s = 0.f;
        for (int i = 0; i < W; i++) s += attnw[i][t];
        colsum[t] = s;
    }
    __syncthreads();

    {
        float acc[S] = {};
        #pragma unroll
        for (int i = 0; i < W; i++) {
            float vx = bu2f(vbuf[bw + (size_t)i * 256 + t]);   // direct global
            float4 w0 = *(const float4*)&attnw[i][0];
            float4 w1 = *(const float4*)&attnw[i][4];
            acc[0] += w0.x * vx; acc[1] += w0.y * vx;
            acc[2] += w0.z * vx; acc[3] += w0.w * vx;
            acc[4] += w1.x * vx; acc[5] += w1.y * vx;
            acc[6] += w1.z * vx; acc[7] += w1.w * vx;
        }
        #pragma unroll
        for (int j = 0; j < S; j++) us[j * 257 + t] = acc[j] / colsum[j];
    }
    __syncthreads();

    {
        int lane = t & 63;
        #pragma unroll
        for (int jj = 0; jj < 2; jj++) {
            int j = (t >> 6) * 2 + jj;
            float x0 = us[j * 257 + lane],       x1 = us[j * 257 + lane + 64];
            float x2 = us[j * 257 + lane + 128], x3 = us[j * 257 + lane + 192];
            float p = x0 + x1 + x2 + x3;
            for (int off = 32; off; off >>= 1) p += __shfl_xor(p, off);
            float mean = p * (1.f / 256.f);
            float d0 = x0 - mean, d1 = x1 - mean, d2 = x2 - mean, d3 = x3 - mean;
            float vr = d0 * d0 + d1 * d1 + d2 * d2 + d3 * d3;
            for (int off = 32; off; off >>= 1) vr += __shfl_xor(vr, off);
            if (lane == 0) {
                mean_s[j] = mean;
                rstd_s[j] = rsqrtf(vr * (1.f / 256.f) + 1e-5f);
            }
        }
    }
    __syncthreads();

    {
        float g = g_ln[t], bb = b_ln[t];
        #pragma unroll
        for (int j = 0; j < S; j++)
            ubuf[bs + j * 256 + t] = f2bu((us[j * 257 + t] - mean_s[j]) * rstd_s[j] * g + bb);
    }
}

// ---------------- fallback: round-4 proven mega-kernel ----------------
__global__ __launch_bounds__(256) void mega_kernel(
    const float* __restrict__ sentence, const float* __restrict__ sent_sum,
    const int*  __restrict__ mask,
    const float* __restrict__ Wk, const float* __restrict__ bk,
    const float* __restrict__ Wv, const float* __restrict__ bv,
    const float* __restrict__ Wq, const float* __restrict__ bq,
    const float* __restrict__ g_ln, const float* __restrict__ b_ln,
    const float* __restrict__ W1, const float* __restrict__ b1,
    const float* __restrict__ W2, const float* __restrict__ b2,
    const float* __restrict__ Wbind, const float* __restrict__ bbind,
    const float* __restrict__ Wproj, const float* __restrict__ bproj,
    float* __restrict__ out)
{
    const int W = 24, S = 8, D = 256, IN = 512, H = 512;
    __shared__ float seh[2048];
    __shared__ ushort kk[24 * 256];
    __shared__ ushort vv[24 * 256];
    __shared__ float is0s[8 * 256];
    __shared__ float sl[8 * 256];
    __shared__ float qv[8 * 256];
    __shared__ float attnw[24][8];
    __shared__ float colsum[8], mean_s[8], rstd_s[8], maskf[24];

    int nb = blockIdx.x, t = threadIdx.x;
    size_t sbase = (size_t)nb * W * IN;

    if (t < W) maskf[t] = mask[(size_t)nb * W + t] ? 0.f : -1e6f;
    for (int l = t; l < IN; l += 256) seh[l] = sent_sum[(size_t)nb * IN + l];
    __syncthreads();
    {
        float acc[S];
        #pragma unroll
        for (int j = 0; j < S; j++) acc[j] = bbind[j * D + t];
        for (int c = 0; c < IN; c++) {
            float sc = seh[c];
            #pragma unroll
            for (int j = 0; j < S; j++) acc[j] += sc * Wbind[(size_t)c * (S * D) + j * D + t];
        }
        #pragma unroll
        for (int j = 0; j < S; j++) { is0s[j * D + t] = acc[j]; sl[j * D + t] = acc[j]; }
    }
    {
        float ka[W], va[W];
        float bkv = bk[t], bvv = bv[t];
        #pragma unroll
        for (int i = 0; i < W; i++) { ka[i] = bkv; va[i] = bvv; }
        for (int ch = 0; ch < 8; ch++) {
            __syncthreads();
            for (int l = t; l < W * 64; l += 256) {
                int i = l >> 6, c = l & 63;
                seh[l] = sentence[sbase + (size_t)i * IN + ch * 64 + c];
            }
            __syncthreads();
            for (int c = 0; c < 64; c++) {
                int cg = ch * 64 + c;
                float wk = Wk[(size_t)cg * D + t];
                float wv = Wv[(size_t)cg * D + t];
                #pragma unroll
                for (int i = 0; i < W; i++) {
                    float s = seh[i * 64 + c];
                    ka[i] += s * wk; va[i] += s * wv;
                }
            }
        }
        #pragma unroll
        for (int i = 0; i < W; i++) {
            float kx = ka[i];
            kk[i * D + t] = f2bu(kx > 0.f ? kx + 1.f : expf(kx));
            vv[i * D + t] = f2bu(va[i]);
        }
    }
    __syncthreads();

    for (int it = 0; it < 3; it++) {
        {
            float qa[S]; float bqv = bq[t];
            #pragma unroll
            for (int j = 0; j < S; j++) qa[j] = bqv + is0s[j * D + t];
            for (int c = 0; c < D; c++) {
                float wq = Wq[(size_t)c * D + t];
                #pragma unroll
                for (int j = 0; j < S; j++) qa[j] += sl[j * D + c] * wq;
            }
            #pragma unroll
            for (int j = 0; j < S; j++) {
                float y = qa[j] * 0.0625f;
                qv[j * D + t] = y > 0.f ? y + 1.f : expf(y);
            }
        }
        __syncthreads();
        if (t < W * S) {
            int i = t >> 3, j = t & 7;
            float a = 0.f;
            #pragma unroll 8
            for (int d = 0; d < D; d++) a += bu2f(kk[i * D + d]) * qv[j * D + d];
            attnw[i][j] = a + maskf[i];
        }
        __syncthreads();
        if (t < W) {
            float m = attnw[t][0];
            #pragma unroll
            for (int j = 1; j < S; j++) m = fmaxf(m, attnw[t][j]);
            float e[S]; float s = 0.f;
            #pragma unroll
            for (int j = 0; j < S; j++) { e[j] = expf(attnw[t][j] - m); s += e[j]; }
            #pragma unroll
            for (int j = 0; j < S; j++) attnw[t][j] = e[j] / s + 1e-6f;
        }
        __syncthreads();
        if (t < S) {
            float s = 0.f;
            for (int i = 0; i < W; i++) s += attnw[i][t];
            colsum[t] = s;
        }
        __syncthreads();
        {
            float acc[S] = {};
            #pragma unroll
            for (int i = 0; i < W; i++) {
                float vx = bu2f(vv[i * D + t]);
                #pragma unroll
                for (int j = 0; j < S; j++) acc[j] += attnw[i][j] * vx;
            }
            #pragma unroll
            for (int j = 0; j < S; j++) qv[j * D + t] = acc[j] / colsum[j];
        }
        __syncthreads();
        {
            int lane = t & 63;
            #pragma unroll
            for (int jj = 0; jj < 2; jj++) {
                int j = (t >> 6) * 2 + jj;
                float x0 = qv[j * D + lane],       x1 = qv[j * D + lane + 64];
                float x2 = qv[j * D + lane + 128], x3 = qv[j * D + lane + 192];
                float p = x0 + x1 + x2 + x3;
                for (int off = 32; off; off >>= 1) p += __shfl_xor(p, off);
                float mean = p * (1.f / 256.f);
                float d0 = x0 - mean, d1 = x1 - mean, d2 = x2 - mean, d3 = x3 - mean;
                float vr = d0 * d0 + d1 * d1 + d2 * d2 + d3 * d3;
                for (int off = 32; off; off >>= 1) vr += __shfl_xor(vr, off);
                if (lane == 0) { mean_s[j] = mean; rstd_s[j] = rsqrtf(vr * (1.f / 256.f) + 1e-5f); }
            }
        }
        __syncthreads();
        {
            float g = g_ln[t], bb = b_ln[t];
            #pragma unroll
            for (int j = 0; j < S; j++)
                qv[j * D + t] = (qv[j * D + t] - mean_s[j]) * rstd_s[j] * g + bb;
        }
        __syncthreads();
        {
            float sa[S]; float b2v = b2[t];
            #pragma unroll
            for (int j = 0; j < S; j++) sa[j] = b2v;
            for (int half = 0; half < 2; half++) {
                int hcol = half * 256 + t;
                float ha[S]; float b1v = b1[hcol];
                #pragma unroll
                for (int j = 0; j < S; j++) ha[j] = b1v;
                for (int d = 0; d < D; d++) {
                    float w1 = W1[(size_t)d * H + hcol];
                    #pragma unroll
                    for (int j = 0; j < S; j++) ha[j] += qv[j * D + d] * w1;
                }
                __syncthreads();
                #pragma unroll
                for (int j = 0; j < S; j++) seh[j * D + t] = fmaxf(ha[j], 0.f);
                __syncthreads();
                for (int h = 0; h < 256; h++) {
                    float w2 = W2[(size_t)(half * 256 + h) * D + t];
                    #pragma unroll
                    for (int j = 0; j < S; j++) sa[j] += seh[j * D + h] * w2;
                }
            }
            __syncthreads();
            #pragma unroll
            for (int j = 0; j < S; j++) sl[j * D + t] += sa[j] * (1.f / 256.f);
        }
        __syncthreads();
    }
    {
        float oa[S]; float bpv = bproj[t];
        #pragma unroll
        for (int j = 0; j < S; j++) oa[j] = bpv;
        for (int c = 0; c < D; c++) {
            float wp1 = Wproj[(size_t)c * D + t];
            float wp2 = Wproj[(size_t)(D + c) * D + t];
            #pragma unroll
            for (int j = 0; j < S; j++)
                oa[j] += is0s[j * D + c] * wp1 + sl[j * D + c] * wp2;
        }
        #pragma unroll
        for (int j = 0; j < S; j++)
            out[(size_t)nb * (S * D) + j * D + t] = oa[j];
    }
}

extern "C" void kernel_launch(void* const* d_in, const int* in_sizes, int n_in,
                              void* d_out, int out_size, void* d_ws, size_t ws_size,
                              hipStream_t stream)
{
    const float* sentence = (const float*)d_in[0];
    const float* sent_sum = (const float*)d_in[1];
    const int*  mask      = (const int*)d_in[2];
    const float* Wk = (const float*)d_in[3];  const float* bk = (const float*)d_in[4];
    const float* Wv = (const float*)d_in[5];  const float* bv = (const float*)d_in[6];
    const float* Wq = (const float*)d_in[7];  const float* bq = (const float*)d_in[8];
    const float* g_ln = (const float*)d_in[9];  const float* b_ln = (const float*)d_in[10];
    const float* W1 = (const float*)d_in[11]; const float* b1 = (const float*)d_in[12];
    const float* W2 = (const float*)d_in[13]; const float* b2 = (const float*)d_in[14];
    const float* Wbind = (const float*)d_in[15]; const float* bbind = (const float*)d_in[16];
    const float* Wproj = (const float*)d_in[17]; const float* bproj = (const float*)d_in[18];
    float* out = (float*)d_out;

    const size_t WS_NEEDED = 123076608ULL;
    if (ws_size >= WS_NEEDED) {
        char* w = (char*)d_ws;
        float*  slots   = (float*) (w);                 // 16 MB  [16384,256] f32
        ushort* catb    = (ushort*)(w + 16777216);      // 16 MB  [16384,512] = [is0|slots] bf16
        ushort* kbuf    = (ushort*)(w + 33554432);      // 24 MB  [49152,256]
        ushort* vbuf    = (ushort*)(w + 58720256);      // 24 MB
        ushort* qbuf    = (ushort*)(w + 83886080);      //  8 MB
        ushort* ubuf    = (ushort*)(w + 92274688);      //  8 MB
        ushort* hbuf    = (ushort*)(w + 100663296);     // 16 MB  [16384,512]
        ushort* ssum_bf = (ushort*)(w + 117440512);     //  2 MB
        ushort* Wbind_t = (ushort*)(w + 119537664);
        ushort* Wkv_t   = (ushort*)(w + 121634816);
        ushort* Wq_t    = (ushort*)(w + 122159104);
        ushort* W1_t    = (ushort*)(w + 122290176);
        ushort* W2_t    = (ushort*)(w + 122552320);
        ushort* Wproj_t = (ushort*)(w + 122814464);

        // sentence-bf16 lives in regions that are dead until after gemm_kv64:
        //   rows 0..32767  -> slots+catb   (32 MB; first written by gemm64<IS0>)
        //   rows 32768..   -> qbuf+ubuf    (16 MB; first written in iteration 1)
        ushort* sentA0 = (ushort*)(w);
        ushort* sentA1 = (ushort*)(w + 83886080);

        prep_kernel<<<dim3(32512), dim3(256), 0, stream>>>(
            sentence, sent_sum, Wbind, Wk, Wv, Wq, W1, W2, Wproj,
            sentA0, sentA1,
            ssum_bf, Wbind_t, Wkv_t, Wq_t, W1_t, W2_t, Wproj_t);

        gemm_kv64<<<dim3(6144), dim3(256), 0, stream>>>(
            sentA0, sentA1, Wkv_t, bk, bv, kbuf, vbuf, 512);

        // is0 = ssum @ Wbind + bbind -> slots f32 + both catb halves
        gemm64<GEPI_IS0, 32><<<dim3(1024), dim3(256), 0, stream>>>(
            ssum_bf, 512, Wbind_t, bbind,
            slots, catb, nullptr, 2048, 2048, 512);

        for (int it = 0; it < 3; it++) {
            gemm64<GEPI_Q, 4><<<dim3(1024), dim3(256), 0, stream>>>(
                catb + 256, 512, Wq_t, bq,
                nullptr, qbuf, catb, 16384, 256, 256);
            attn_kernel<<<dim3(2048), dim3(256), 0, stream>>>(
                kbuf, vbuf, qbuf, mask, g_ln, b_ln, ubuf);
            gemm64<GEPI_RELU, 8><<<dim3(2048), dim3(256), 0, stream>>>(
                ubuf, 256, W1_t, b1,
                nullptr, hbuf, nullptr, 16384, 512, 256);
            if (it < 2)
                gemm64<GEPI_MLP2, 4><<<dim3(1024), dim3(256), 0, stream>>>(
                    hbuf, 512, W2_t, b2,
                    slots, catb, nullptr, 16384, 256, 512);
            else
                gemm64<GEPI_MLP2L, 4><<<dim3(1024), dim3(256), 0, stream>>>(
                    hbuf, 512, W2_t, b2,
                    slots, catb, nullptr, 16384, 256, 512);
        }

        gemm64<GEPI_OUT, 4><<<dim3(1024), dim3(256), 0, stream>>>(
            catb, 512, Wproj_t, bproj,
            out, nullptr, nullptr, 16384, 256, 512);
    } else {
        mega_kernel<<<dim3(2048), dim3(256), 0, stream>>>(
            sentence, sent_sum, mask, Wk, bk, Wv, bv, Wq, bq, g_ln, b_ln,
            W1, b1, W2, b2, Wbind, bbind, Wproj, bproj, out);
    }
}